// Round 6
// baseline (126.223 us; speedup 1.0000x reference)
//
#include <hip/hip_runtime.h>
#include <math.h>

#define LSEQ 128
#define NLL 16384      // L*L
#define NBATCH 4
#define DIM 768
#define NB 4
#define ALPHA_C 32.0f
#define MRG_C 0.05f
#define CLW_C 0.05f
#define BPB 128        // blocks per batch per table (512/4)
#define KS 24          // 768 floats / (8 lanes * 4 floats)

__device__ __forceinline__ float wave_reduce_f(float v) {
#pragma unroll
    for (int s = 1; s < 64; s <<= 1) v += __shfl_xor(v, s);
    return v;
}

__device__ __forceinline__ float dot4(float4 a, float4 b) {
    return a.x*b.x + a.y*b.y + a.z*b.z + a.w*b.w;
}

// 8 lanes per row, 4 rows per lane-group -> 32 rows/wave, 128 rows per block.
// Each weight ds_read_b128 feeds 4 row-accumulations.
template<bool EDGE>
__device__ __forceinline__ void kloop4(const float* __restrict__ rp,
                                       const float* __restrict__ wlds, int sub,
                                       float (&xx)[4], float (&d0)[4], float (&d1)[4],
                                       float (&d2)[4], float (&d3)[4],
                                       float (&dS)[4], float (&dE)[4])
{
#pragma unroll 2
    for (int k = 0; k < KS; ++k) {
        const int off = k*32 + sub*4;
        float4 x[4];
#pragma unroll
        for (int rr = 0; rr < 4; ++rr)
            x[rr] = *reinterpret_cast<const float4*>(rp + (size_t)rr*DIM + off);
        const float4 w0 = *reinterpret_cast<const float4*>(&wlds[0*DIM + off]);
        const float4 w1 = *reinterpret_cast<const float4*>(&wlds[1*DIM + off]);
        const float4 w2 = *reinterpret_cast<const float4*>(&wlds[2*DIM + off]);
        const float4 w3 = *reinterpret_cast<const float4*>(&wlds[3*DIM + off]);
        float4 w4, w5;
        if constexpr (EDGE) {
            w4 = *reinterpret_cast<const float4*>(&wlds[4*DIM + off]);
            w5 = *reinterpret_cast<const float4*>(&wlds[5*DIM + off]);
        }
#pragma unroll
        for (int rr = 0; rr < 4; ++rr) {
            xx[rr] += dot4(x[rr], x[rr]);
            d0[rr] += dot4(x[rr], w0);
            d1[rr] += dot4(x[rr], w1);
            d2[rr] += dot4(x[rr], w2);
            d3[rr] += dot4(x[rr], w3);
            if constexpr (EDGE) { dS[rr] += dot4(x[rr], w4); dE[rr] += dot4(x[rr], w5); }
        }
    }
}

// grid 1024: tbl = bid&1 (0=edge,1=senti), g = bid>>1 in [0,512). 128 rows/block.
__global__ __launch_bounds__(256, 4)
void fused_pass(const float* __restrict__ tabE, const float* __restrict__ tabS,
                const int* __restrict__ labE, const int* __restrict__ labSen,
                const int* __restrict__ attn,
                const float* __restrict__ proxE, const float* __restrict__ proxSen,
                const float* __restrict__ wS, const float* __restrict__ bS,
                const float* __restrict__ wE, const float* __restrict__ bE,
                const int* __restrict__ tlabS, const int* __restrict__ tlabE,
                float* __restrict__ pS, float* __restrict__ pE,
                float* __restrict__ partE, float* __restrict__ partSen)
{
    __shared__ float wlds[6*DIM];      // 18432 B
    __shared__ float red[4][7*32];     // per-wave [slot][row]: 3584 B
    __shared__ float sacc[4][14];

    const int tid = threadIdx.x, wib = tid >> 6, lane = tid & 63;
    const int tbl = blockIdx.x & 1;
    const int g = blockIdx.x >> 1;     // [0,512)
    const int row0 = g << 7;           // 128 rows per block
    const int b = g >> 7;              // batch
    const bool EDGE = (tbl == 0);

    const float* table = EDGE ? tabE : tabS;
    const float* prox  = EDGE ? proxE : proxSen;
    const int NW = EDGE ? 6 : 4;

    // cooperative weight load into LDS
    for (int i2 = tid; i2 < NW*192; i2 += 256) {
        const int v = i2 / 192, e = (i2 % 192) * 4;
        const float* src = (v < 4) ? (prox + v*DIM + e) : ((v == 4) ? (wS + e) : (wE + e));
        *reinterpret_cast<float4*>(&wlds[v*DIM + e]) = *reinterpret_cast<const float4*>(src);
    }
    __syncthreads();

    // per-wave: lens + proxy inverse norms (registers, no cross-wave deps)
    int lens_i = attn[b*LSEQ + lane] + attn[b*LSEQ + 64 + lane];
#pragma unroll
    for (int s = 1; s < 64; s <<= 1) lens_i += __shfl_xor(lens_i, s);
    float pinv[NB];
#pragma unroll
    for (int c = 0; c < NB; ++c) {
        float s2 = 0.f;
#pragma unroll
        for (int t = 0; t < 12; ++t) { const float w = wlds[c*DIM + t*64 + lane]; s2 += w*w; }
        s2 = wave_reduce_f(s2);
        pinv[c] = 1.0f / fmaxf(sqrtf(s2), 1e-12f);
    }

    // ---------- main loop ----------
    const int rgrp = lane >> 3, sub = lane & 7;
    const int rbase = row0 + wib*32 + rgrp*4;
    const float* rp = table + (size_t)rbase * DIM;

    float xx[4]={0,0,0,0}, d0[4]={0,0,0,0}, d1[4]={0,0,0,0}, d2[4]={0,0,0,0},
          d3[4]={0,0,0,0}, dS[4]={0,0,0,0}, dE[4]={0,0,0,0};
    if (EDGE) kloop4<true >(rp, wlds, sub, xx, d0, d1, d2, d3, dS, dE);
    else      kloop4<false>(rp, wlds, sub, xx, d0, d1, d2, d3, dS, dE);

    // 3-stage reduce across the 8-lane group
#pragma unroll
    for (int s = 1; s < 8; s <<= 1) {
#pragma unroll
        for (int rr = 0; rr < 4; ++rr) {
            xx[rr] += __shfl_xor(xx[rr], s);
            d0[rr] += __shfl_xor(d0[rr], s); d1[rr] += __shfl_xor(d1[rr], s);
            d2[rr] += __shfl_xor(d2[rr], s); d3[rr] += __shfl_xor(d3[rr], s);
        }
        if (EDGE) {
#pragma unroll
            for (int rr = 0; rr < 4; ++rr) {
                dS[rr] += __shfl_xor(dS[rr], s); dE[rr] += __shfl_xor(dE[rr], s);
            }
        }
    }
    if (sub == 0) {
        float* rw = red[wib];
        const int rb = rgrp*4;
        *reinterpret_cast<float4*>(&rw[0*32+rb]) = make_float4(xx[0],xx[1],xx[2],xx[3]);
        *reinterpret_cast<float4*>(&rw[1*32+rb]) = make_float4(d0[0],d0[1],d0[2],d0[3]);
        *reinterpret_cast<float4*>(&rw[2*32+rb]) = make_float4(d1[0],d1[1],d1[2],d1[3]);
        *reinterpret_cast<float4*>(&rw[3*32+rb]) = make_float4(d2[0],d2[1],d2[2],d2[3]);
        *reinterpret_cast<float4*>(&rw[4*32+rb]) = make_float4(d3[0],d3[1],d3[2],d3[3]);
        if (EDGE) {
            *reinterpret_cast<float4*>(&rw[5*32+rb]) = make_float4(dS[0],dS[1],dS[2],dS[3]);
            *reinterpret_cast<float4*>(&rw[6*32+rb]) = make_float4(dE[0],dE[1],dE[2],dE[3]);
        }
    }
    asm volatile("s_waitcnt lgkmcnt(0)" ::: "memory");   // same-wave LDS visibility

    // ---------- per-wave epilogue: 32 rows on lanes 0..31 ----------
    float Pa[NB]={0,0,0,0}, Na[NB]={0,0,0,0}, Ca[NB]={0,0,0,0};
    float sBS = 0.f, sBE = 0.f;
    if (lane < 32) {
        const int r = row0 + wib*32 + lane;       // row within this table
        const float* rw = red[wib];
        const float xxv = rw[lane];
        float dd[NB] = { rw[32+lane], rw[64+lane], rw[96+lane], rw[128+lane] };
        const float xinv = 1.0f / fmaxf(sqrtf(xxv), 1e-12f);
        const int i = r & (NLL - 1);
        const int l = i >> 7, m = i & (LSEQ - 1);
        const bool valid = (l >= 1) && (l < lens_i - 1) && (m >= 1) && (m < lens_i - 1);
        const int lab = (EDGE ? labE : labSen)[r];
        if (valid) {
#pragma unroll
            for (int c = 0; c < NB; ++c) {
                const float cs = dd[c] * xinv * pinv[c];
                if (lab == c) { Pa[c] = expf(-ALPHA_C * (cs - MRG_C)); Ca[c] = 1.f; }
                else          { Na[c] = expf( ALPHA_C * (cs + MRG_C)); }
            }
        }
        if (EDGE) {
            const float dSl = rw[160+lane], dEl = rw[192+lane];
            const float xSl = dSl + bS[0], xEl = dEl + bE[0];
            const int ls = tlabS[r], le = tlabE[r];
            const float w = (ls >= 0) ? 1.f : 0.f;
            const float spS = fmaxf(xSl, 0.f) + log1pf(expf(-fabsf(xSl)));
            const float spE = fmaxf(xEl, 0.f) + log1pf(expf(-fabsf(xEl)));
            sBS = w * (spS - xSl * (float)ls);
            sBE = w * (spE - xEl * (float)le);
            pS[r] = w / (1.f + expf(-xSl));
            pE[r] = w / (1.f + expf(-xEl));
        }
    }
#pragma unroll
    for (int c = 0; c < NB; ++c) {
        Pa[c] = wave_reduce_f(Pa[c]); Na[c] = wave_reduce_f(Na[c]); Ca[c] = wave_reduce_f(Ca[c]);
    }
    sBS = wave_reduce_f(sBS); sBE = wave_reduce_f(sBE);
    if (lane == 0) {
        float* sp = sacc[wib];
#pragma unroll
        for (int c = 0; c < NB; ++c) { sp[c] = Pa[c]; sp[4+c] = Na[c]; sp[8+c] = Ca[c]; }
        sp[12] = sBS; sp[13] = sBE;
    }
    __syncthreads();
    if (tid < 14) {
        const float s = sacc[0][tid] + sacc[1][tid] + sacc[2][tid] + sacc[3][tid];
        float* pp = EDGE ? partE : partSen;
        const int blk = g & (BPB - 1);
        pp[(b * 14 + tid) * BPB + blk] = s;
    }
}

// 10 blocks: 0-7 = prune (exact k-th largest), 8-9 = finalize (scalar outputs).
__global__ __launch_bounds__(1024)
void tail_k(const float* __restrict__ pS, const float* __restrict__ pE,
            const int* __restrict__ attn,
            const float* __restrict__ partE, const float* __restrict__ partS,
            float* __restrict__ out)
{
    __shared__ unsigned sh[NLL];     // 64 KB (prune path)
    __shared__ int csum[16];
    __shared__ float gg[56];
    const int tid = threadIdx.x, wave = tid >> 6, lane = tid & 63;

    if (blockIdx.x >= 8) {
        const int tbl = blockIdx.x - 8;
        const float* part = (tbl == 0) ? partE : partS;
        for (int grp = wave; grp < 56; grp += 16) {
            float s = 0.f;
#pragma unroll
            for (int j = lane; j < BPB; j += 64) s += part[grp*BPB + j];
            s = wave_reduce_f(s);
            if (lane == 0) gg[grp] = s;
        }
        __syncthreads();
        if (tid == 0) {
            float tot = 0.f;
            for (int b = 0; b < NBATCH; ++b) {
                const float* G = gg + b * 14;
                int nv = 0;
                for (int c = 0; c < NB; ++c) nv += (G[8+c] > 0.f) ? 1 : 0;
                const float nvf = (float)((nv > 1) ? nv : 1);
                float pos = 0.f, neg = 0.f;
                for (int c = 0; c < NB; ++c) { pos += log1pf(G[c]); neg += log1pf(G[4+c]); }
                tot += pos / nvf + neg * 0.25f;
            }
            out[tbl] = CLW_C * tot * 0.25f;
            if (tbl == 0) {
                float bs = 0.f, be = 0.f;
                for (int b = 0; b < NBATCH; ++b) { bs += gg[b*14 + 12]; be += gg[b*14 + 13]; }
                out[2] = bs * (1.0f / 65536.0f);
                out[3] = be * (1.0f / 65536.0f);
            }
        }
        return;
    }

    const int a = blockIdx.x >> 2;   // 0 = S, 1 = E
    const int b = blockIdx.x & 3;
    const float* p = (a ? pE : pS) + (size_t)b * NLL;
    float* o = out + 4 + (size_t)a * (NBATCH * NLL) + (size_t)b * NLL;

    int asum = attn[b*LSEQ + lane] + attn[b*LSEQ + 64 + lane];
#pragma unroll
    for (int s = 1; s < 64; s <<= 1) asum += __shfl_xor(asum, s);
    const int mask_len = asum - 2;
    int k = (int)((float)mask_len * 0.3f);
    k = (k > 10) ? k : 10;
    const int ml2 = mask_len * mask_len;
    k = (k < ml2) ? k : ml2;

    for (int j = tid; j < NLL; j += 1024) sh[j] = __float_as_uint(p[j]);
    __syncthreads();

    unsigned lo = 0u, hi = 0xFFFFFFFFu;
    for (int it = 0; it < 32; ++it) {
        if (lo >= hi) break;                       // uniform across block
        const unsigned span = hi - lo;
        const unsigned mid = lo + (span >> 1) + (span & 1u);   // ceil midpoint, > lo
        int c = 0;
        for (int j = tid; j < NLL; j += 1024) c += (sh[j] >= mid) ? 1 : 0;
#pragma unroll
        for (int s = 1; s < 64; s <<= 1) c += __shfl_xor(c, s);
        if (lane == 0) csum[wave] = c;
        __syncthreads();
        int tot = 0;
#pragma unroll
        for (int w = 0; w < 16; ++w) tot += csum[w];
        if (tot >= k) lo = mid; else hi = mid - 1u;
        __syncthreads();
    }

    for (int j = tid; j < NLL; j += 1024) o[j] = (sh[j] >= lo) ? 1.0f : 0.0f;
}

extern "C" void kernel_launch(void* const* d_in, const int* in_sizes, int n_in,
                              void* d_out, int out_size, void* d_ws, size_t ws_size,
                              hipStream_t stream)
{
    const float* table_edge  = (const float*)d_in[0];
    const float* table_senti = (const float*)d_in[1];
    const int*   attn        = (const int*)d_in[2];
    const int*   tlabS       = (const int*)d_in[3];
    const int*   tlabE       = (const int*)d_in[4];
    const int*   lab_edge    = (const int*)d_in[5];
    const int*   lab_senti   = (const int*)d_in[6];
    const float* prox_edge   = (const float*)d_in[7];
    const float* prox_senti  = (const float*)d_in[8];
    const float* w_S         = (const float*)d_in[9];
    const float* b_S         = (const float*)d_in[10];
    const float* w_E         = (const float*)d_in[11];
    const float* b_E         = (const float*)d_in[12];

    float* out   = (float*)d_out;
    float* ws    = (float*)d_ws;
    float* pS    = ws;                      // 65536
    float* pE    = ws + 65536;              // 65536
    float* partE = ws + 131072;             // 4*14*128 = 7168
    float* partS = partE + 7168;            // 7168

    fused_pass<<<1024, 256, 0, stream>>>(table_edge, table_senti,
        lab_edge, lab_senti, attn, prox_edge, prox_senti,
        w_S, b_S, w_E, b_E, tlabS, tlabE, pS, pE, partE, partS);
    tail_k<<<10, 1024, 0, stream>>>(pS, pE, attn, partE, partS, out);
}